// Round 3
// baseline (421.010 us; speedup 1.0000x reference)
//
#include <hip/hip_runtime.h>
#include <stdint.h>

#define DIN   63
#define BATCH 256
#define H1    256
#define H2    128
#define NEG   0.1f
#define EPSB  1e-5f

typedef _Float16 half2_t __attribute__((ext_vector_type(2)));
typedef _Float16 half4_t __attribute__((ext_vector_type(4)));
typedef _Float16 half8_t __attribute__((ext_vector_type(8)));
typedef float   float4_t __attribute__((ext_vector_type(4)));

#define V12_STRIDE 66        // halves per b-row (64 j + 2 pad; keeps ds_read_b32 4B-aligned)
#define WTS        136       // halves per n-row of a W tile: 128 k + 8 pad (16B-aligned k-runs)
#define WT_BUF     (32 * WTS)

union AFrag { half8_t v; half2_t h2[4]; };

static __device__ __forceinline__ half2_t pack_f16(float a, float b) {
    half2_t h; h.x = (_Float16)a; h.y = (_Float16)b; return h;
}

// GEMM1: C[b,h] partial for one i-slab. A = x (on-the-fly), M=256, N=32 cols, K=4096.
// K-loop: 32 iters x 128 rows; single barrier per iter; 2-iter-deep register prefetch.
__global__ __launch_bounds__(256, 2)
void gemm1_kernel(const float* __restrict__ vec1, const float* __restrict__ vec2,
                  const float* __restrict__ vec3, const float* __restrict__ W1,
                  float* __restrict__ partial)
{
    const int nt    = blockIdx.x;          // 0..7   -> n0 = nt*32
    const int islab = blockIdx.y;          // 0..63  -> i
    const int n0    = nt * 32;
    const int tid   = threadIdx.x;
    const int lane  = tid & 63;
    const int wm    = tid >> 6;            // wave id -> M quarter
    const int m16   = lane & 15;
    const int quad  = lane >> 4;

    __shared__ __align__(16) _Float16 v12all[BATCH * V12_STRIDE];  // 33792 B
    __shared__ __align__(16) _Float16 Wt[2 * WT_BUF];              // 17408 B

    // ---- W-load mapping: lanes 0..7 cover one row's 128B chunk densely.
    // thread -> rows rr..rr+3 (k), cols c..c+3 (n). 4x float4 per iter.
    const int rr = (tid >> 3) * 4;                 // 0,4,...,124
    const int cl = (tid & 7) * 4;                  // local n: 0,4,...,28
    const float* wload_base = W1 + ((size_t)islab * 4096 + rr) * H1 + n0 + cl;

    float4_t t0[4], pA[4], pB[4];
    {   // issue steps 0,1,2 immediately so HBM flows under the preamble
        #pragma unroll
        for (int r = 0; r < 4; ++r) t0[r] = *(const float4_t*)(wload_base + (size_t)r * H1);
        const float* p1 = wload_base + (size_t)128 * H1;
        #pragma unroll
        for (int r = 0; r < 4; ++r) pA[r] = *(const float4_t*)(p1 + (size_t)r * H1);
        const float* p2 = wload_base + (size_t)256 * H1;
        #pragma unroll
        for (int r = 0; r < 4; ++r) pB[r] = *(const float4_t*)(p2 + (size_t)r * H1);
    }

    // ---- one-time: v12all[b][j] = v1e[b,islab] * v2e[b,j]   (fp16 RTE)
    {
        const int b = tid;
        const float v1v = (islab < DIN) ? vec1[b * DIN + islab] : 1.0f;
        #pragma unroll
        for (int jp = 0; jp < 32; ++jp) {
            const int j0 = 2 * jp;
            const float a0 = v1v * ((j0     < DIN) ? vec2[b * DIN + j0    ] : 1.0f);
            const float a1 = v1v * ((j0 + 1 < DIN) ? vec2[b * DIN + j0 + 1] : 1.0f);
            *reinterpret_cast<half2_t*>(&v12all[b * V12_STRIDE + j0]) = pack_f16(a0, a1);
        }
    }

    // ---- one-time: v3 in registers in MFMA A-frag k-run layout
    half2_t v3h[4][2][4];   // [Mt][kk][pair]
    #pragma unroll
    for (int Mt = 0; Mt < 4; ++Mt) {
        const int b = wm * 64 + Mt * 16 + m16;
        #pragma unroll
        for (int kk = 0; kk < 2; ++kk) {
            const int kb = kk * 32 + quad * 8;
            float v[8];
            #pragma unroll
            for (int t = 0; t < 8; ++t) {
                const int k = kb + t;
                v[t] = (k < DIN) ? vec3[b * DIN + k] : 1.0f;
            }
            #pragma unroll
            for (int s = 0; s < 4; ++s) v3h[Mt][kk][s] = pack_f16(v[2 * s], v[2 * s + 1]);
        }
    }

    // ---- LDS write of a W step (transposed fp16): Wt[n][k], half4 along k
    auto write_step = [&](int buf, const float4_t (&v)[4]) {
        _Float16* wn = &Wt[buf * WT_BUF];
        #pragma unroll
        for (int sc = 0; sc < 4; ++sc) {
            half4_t h;
            h.x = (_Float16)v[0][sc]; h.y = (_Float16)v[1][sc];
            h.z = (_Float16)v[2][sc]; h.w = (_Float16)v[3][sc];
            *reinterpret_cast<half4_t*>(&wn[(cl + sc) * WTS + rr]) = h;
        }
    };

    write_step(0, t0);
    __syncthreads();

    float4_t acc[4][2];
    #pragma unroll
    for (int Mt = 0; Mt < 4; ++Mt)
        #pragma unroll
        for (int Nt = 0; Nt < 2; ++Nt)
            acc[Mt][Nt] = (float4_t){0.f, 0.f, 0.f, 0.f};

    // ---- main loop: iter s covers j = 2s, 2s+1 (128 K-rows)
    auto iter = [&](int s, float4_t (&pend)[4]) {
        const int cur = s & 1;
        const _Float16* wb = &Wt[cur * WT_BUF];

        half8_t bfrag[2][2][2];   // [jj][kk][Nt]
        #pragma unroll
        for (int jj = 0; jj < 2; ++jj)
            #pragma unroll
            for (int kk = 0; kk < 2; ++kk)
                #pragma unroll
                for (int Nt = 0; Nt < 2; ++Nt)
                    bfrag[jj][kk][Nt] = *reinterpret_cast<const half8_t*>(
                        &wb[(Nt * 16 + m16) * WTS + jj * 64 + kk * 32 + quad * 8]);

        half2_t vj[4];
        #pragma unroll
        for (int Mt = 0; Mt < 4; ++Mt)
            vj[Mt] = *reinterpret_cast<const half2_t*>(
                &v12all[(wm * 64 + Mt * 16 + m16) * V12_STRIDE + 2 * s]);

        if (s < 31) write_step(cur ^ 1, pend);      // stage step s+1 (loaded 2 iters ago)
        if (s < 29) {                               // issue loads for step s+3
            const float* p = wload_base + (size_t)(s + 3) * 128 * H1;
            #pragma unroll
            for (int r = 0; r < 4; ++r) pend[r] = *(const float4_t*)(p + (size_t)r * H1);
        }
        __syncthreads();

        #pragma unroll
        for (int jj = 0; jj < 2; ++jj)
            #pragma unroll
            for (int Mt = 0; Mt < 4; ++Mt) {
                half2_t vv; vv.x = vj[Mt][jj]; vv.y = vj[Mt][jj];
                #pragma unroll
                for (int kk = 0; kk < 2; ++kk) {
                    AFrag af;
                    #pragma unroll
                    for (int sc = 0; sc < 4; ++sc) af.h2[sc] = vv * v3h[Mt][kk][sc];
                    acc[Mt][0] = __builtin_amdgcn_mfma_f32_16x16x32_f16(af.v, bfrag[jj][kk][0], acc[Mt][0], 0, 0, 0);
                    acc[Mt][1] = __builtin_amdgcn_mfma_f32_16x16x32_f16(af.v, bfrag[jj][kk][1], acc[Mt][1], 0, 0, 0);
                }
            }
    };

    #pragma unroll 1
    for (int s2 = 0; s2 < 32; s2 += 2) {
        iter(s2,     pA);
        iter(s2 + 1, pB);
    }

    // ---- store partial tile: D layout n=lane&15, m=quad*4+r
    #pragma unroll
    for (int Mt = 0; Mt < 4; ++Mt) {
        const int brow = wm * 64 + Mt * 16 + quad * 4;
        #pragma unroll
        for (int Nt = 0; Nt < 2; ++Nt) {
            const int n = n0 + Nt * 16 + m16;
            #pragma unroll
            for (int r = 0; r < 4; ++r)
                partial[(size_t)islab * (BATCH * H1) + (size_t)(brow + r) * H1 + n] = acc[Mt][Nt][r];
        }
    }
}

// reduce 64 partial slabs -> leaky+BN1 -> layer2 -> leaky+BN2 -> dot with Wc
__global__ __launch_bounds__(256)
void tail_kernel(const float* __restrict__ partial,
                 const float* __restrict__ b1, const float* __restrict__ g1,
                 const float* __restrict__ be1, const float* __restrict__ rm1,
                 const float* __restrict__ rv1,
                 const float* __restrict__ W2, const float* __restrict__ b2,
                 const float* __restrict__ g2, const float* __restrict__ be2,
                 const float* __restrict__ rm2, const float* __restrict__ rv2,
                 const float* __restrict__ Wc, const float* __restrict__ bc,
                 float* __restrict__ out)
{
    const int b = blockIdx.x;
    const int t = threadIdx.x;
    __shared__ float h1row[H1];
    __shared__ float ph[2][H2];
    __shared__ float h2row[H2];

    float s = 0.0f;
    const float* p = partial + (size_t)b * H1 + t;
    #pragma unroll 8
    for (int i = 0; i < 64; ++i) s += p[(size_t)i * (BATCH * H1)];
    s += b1[t];
    s = (s >= 0.0f) ? s : NEG * s;
    s = (s - rm1[t]) * rsqrtf(rv1[t] + EPSB) * g1[t] + be1[t];
    h1row[t] = s;
    __syncthreads();

    {
        const int n    = t & 127;
        const int half = t >> 7;
        const int h0   = half * 128;
        float acc = 0.0f;
        #pragma unroll 4
        for (int h = 0; h < 128; ++h)
            acc += h1row[h0 + h] * W2[(size_t)(h0 + h) * H2 + n];
        ph[half][n] = acc;
    }
    __syncthreads();
    if (t < H2) {
        float acc = ph[0][t] + ph[1][t] + b2[t];
        acc = (acc >= 0.0f) ? acc : NEG * acc;
        acc = (acc - rm2[t]) * rsqrtf(rv2[t] + EPSB) * g2[t] + be2[t];
        h2row[t] = acc;
    }
    __syncthreads();
    if (t < 64) {
        float v = h2row[t] * Wc[t] + h2row[t + 64] * Wc[t + 64];
        #pragma unroll
        for (int off = 32; off > 0; off >>= 1) v += __shfl_down(v, off);
        if (t == 0) out[b] = v + bc[0];
    }
}

extern "C" void kernel_launch(void* const* d_in, const int* in_sizes, int n_in,
                              void* d_out, int out_size, void* d_ws, size_t ws_size,
                              hipStream_t stream)
{
    const float* vec1 = (const float*)d_in[0];
    const float* vec2 = (const float*)d_in[1];
    const float* vec3 = (const float*)d_in[2];
    const float* W1   = (const float*)d_in[3];
    const float* b1   = (const float*)d_in[4];
    const float* g1   = (const float*)d_in[5];
    const float* be1  = (const float*)d_in[6];
    const float* rm1  = (const float*)d_in[7];
    const float* rv1  = (const float*)d_in[8];
    const float* W2   = (const float*)d_in[9];
    const float* b2   = (const float*)d_in[10];
    const float* g2   = (const float*)d_in[11];
    const float* be2  = (const float*)d_in[12];
    const float* rm2  = (const float*)d_in[13];
    const float* rv2  = (const float*)d_in[14];
    const float* Wc   = (const float*)d_in[15];
    const float* bc   = (const float*)d_in[16];

    float* partial = (float*)d_ws;   // 64 * 256 * 256 * 4 B = 16.8 MB scratch

    gemm1_kernel<<<dim3(8, 64), 256, 0, stream>>>(vec1, vec2, vec3, W1, partial);
    tail_kernel<<<256, 256, 0, stream>>>(partial, b1, g1, be1, rm1, rv1,
                                         W2, b2, g2, be2, rm2, rv2, Wc, bc,
                                         (float*)d_out);
}